// Round 5
// baseline (390.393 us; speedup 1.0000x reference)
//
#include <hip/hip_runtime.h>
#include <hip/hip_bf16.h>

#define ALPHA 0.2f
#define LOG2E 1.44269504088896340736f

typedef float  f32x4 __attribute__((ext_vector_type(4)));
typedef float  f32x2 __attribute__((ext_vector_type(2)));
typedef int    i32x4 __attribute__((ext_vector_type(4)));
typedef int    i32x2 __attribute__((ext_vector_type(2)));
typedef unsigned int u32x2 __attribute__((ext_vector_type(2)));

static __device__ __forceinline__ void mfma_bf16_16x16x32(f32x4& c, i32x4 a, i32x4 b) {
  asm("v_mfma_f32_16x16x32_bf16 %0, %1, %2, %0" : "+v"(c) : "v"(a), "v"(b));
}
static __device__ __forceinline__ unsigned short f2bf(float x) {
  __hip_bfloat16 b = __float2bfloat16(x);
  return *reinterpret_cast<unsigned short*>(&b);
}
static __device__ __forceinline__ unsigned int cvtpk(float lo, float hi) {
  unsigned int r;
  asm("v_cvt_pk_bf16_f32 %0, %1, %2" : "=v"(r) : "v"(lo), "v"(hi));
  return r;
}
static __device__ __forceinline__ float dot4(f32x4 a, f32x4 b) {
  return a.x*b.x + a.y*b.y + a.z*b.z + a.w*b.w;
}

// ---- Kernel A: wt[f][k]=bf16(W[k][f]); v1=log2e*(W@a1), v2=log2e*(W@a2); zero ei/ej ----
__global__ __launch_bounds__(256) void k_setup(const float* __restrict__ W, const float* __restrict__ a,
                                               unsigned short* __restrict__ wt,
                                               float* __restrict__ v1, float* __restrict__ v2,
                                               float* __restrict__ eiej) {
  const int bid = blockIdx.x, tid = threadIdx.x;
  __shared__ float S[32][33];
  if (bid < 256) {               // transpose W -> wt (bf16)
    const int k0 = (bid >> 4) * 32, f0 = (bid & 15) * 32;
    const int r = tid >> 5, c = tid & 31;
    #pragma unroll
    for (int rr = r; rr < 32; rr += 8) S[rr][c] = W[(size_t)(k0 + rr) * 512 + f0 + c];
    __syncthreads();
    #pragma unroll
    for (int rr = r; rr < 32; rr += 8) wt[(size_t)(f0 + rr) * 512 + k0 + c] = f2bf(S[c][rr]);
  } else if (bid < 384) {        // v1/v2
    const int kk = (bid - 256) * 4 + (tid >> 6);
    const int l = tid & 63;
    const float* wr = W + (size_t)kk * 512 + l * 8;
    f32x4 w0 = *(const f32x4*)(wr),            w1 = *(const f32x4*)(wr + 4);
    f32x4 p0 = *(const f32x4*)(a + l*8),       p1 = *(const f32x4*)(a + l*8 + 4);
    f32x4 q0 = *(const f32x4*)(a + 512 + l*8), q1 = *(const f32x4*)(a + 512 + l*8 + 4);
    float s1 = dot4(w0,p0) + dot4(w1,p1);
    float s2 = dot4(w0,q0) + dot4(w1,q1);
    #pragma unroll
    for (int off = 1; off < 64; off <<= 1) { s1 += __shfl_xor(s1, off); s2 += __shfl_xor(s2, off); }
    if (l == 0) { v1[kk] = s1 * LOG2E; v2[kk] = s2 * LOG2E; }
  } else {                       // zero ei+ej (32768 floats, 32 blocks x 1024 floats)
    const int idx = (bid - 384) * 1024 + tid * 4;
    *(f32x4*)(eiej + idx) = (f32x4){0.f,0.f,0.f,0.f};
  }
}

// ---- Kernel B: hT[b][f][n]=bf16(h[b][n][f]); ei/ej via fused dots + atomicAdd -----------
// 8192 blocks (b x 64 n-tiles x 16 f-tiles), 256 thr. Pure bandwidth + small atomics.
__global__ __launch_bounds__(256) void k_prep(const float* __restrict__ h,
                                              const float* __restrict__ v1, const float* __restrict__ v2,
                                              unsigned short* __restrict__ hT,
                                              float* __restrict__ ei, float* __restrict__ ej) {
  const int bid = blockIdx.x, tid = threadIdx.x;
  const int ft = bid & 15, nt = (bid >> 4) & 63, b = bid >> 10;
  __shared__ __align__(16) float S[32][36];

  const int n_loc = tid >> 3, fq = (tid & 7) * 4;
  const f32x4 v = __builtin_nontemporal_load(
      (const f32x4*)(h + (size_t)(b*2048 + nt*32 + n_loc)*512 + ft*32 + fq));
  *(f32x4*)&S[n_loc][fq] = v;

  // fused ei/ej partial dots (exact f32, v pre-scaled by log2e)
  const f32x4 a1 = *(const f32x4*)(v1 + ft*32 + fq);
  const f32x4 a2 = *(const f32x4*)(v2 + ft*32 + fq);
  float s1 = dot4(v, a1), s2 = dot4(v, a2);
  #pragma unroll
  for (int off = 1; off < 8; off <<= 1) { s1 += __shfl_xor(s1, off); s2 += __shfl_xor(s2, off); }
  if ((tid & 7) == 0) {
    atomicAdd(&ei[b*2048 + nt*32 + n_loc], s1);
    atomicAdd(&ej[b*2048 + nt*32 + n_loc], s2);
  }
  __syncthreads();

  const int f_loc = tid >> 3, nq = (tid & 7) * 4;
  u32x2 pk;
  pk.x = cvtpk(S[nq+0][f_loc], S[nq+1][f_loc]);
  pk.y = cvtpk(S[nq+2][f_loc], S[nq+3][f_loc]);
  *(u32x2*)(hT + (size_t)(b*512 + ft*32 + f_loc)*2048 + nt*32 + nq) = pk;
}

// ---- Kernel C: C1[b][i][f] = bf16( (softmax-att @ h)[i][f] ) -----------------------------
// 256 blocks (b=bid&7 -> XCD-local 2MB hT slice), 512 thr = 8 waves; wave w owns 64 f-cols.
// adj bit-packed into LDS [2][64 rows][64B] per 512-j chunk (1 barrier/chunk, 4 total).
// P computed per-lane directly in A-fragment layout (row=l&15, k=(l>>4)*8+e) - no P LDS.
__global__ __launch_bounds__(512, 2) void k_attn(const int* __restrict__ adj,
                                                 const unsigned short* __restrict__ hT,
                                                 const float* __restrict__ ei, const float* __restrict__ ej,
                                                 unsigned short* __restrict__ C1) {
  const int tid = threadIdx.x;
  const int w = tid >> 6, l = tid & 63;
  const int fl = l & 15, kq = l >> 4;
  const int b = blockIdx.x & 7;
  const int i0 = (blockIdx.x >> 3) * 64;

  __shared__ __align__(16) float ejl[2048];
  __shared__ __align__(16) unsigned char abits[2][64][64];
  __shared__ __align__(16) float llds[64];

  for (int idx = tid; idx < 2048; idx += 512) ejl[idx] = ej[b*2048 + idx];

  float eir[4];
  #pragma unroll
  for (int fr = 0; fr < 4; ++fr) eir[fr] = ei[b*2048 + i0 + fr*16 + fl];

  const unsigned short* bp[4];
  #pragma unroll
  for (int cf = 0; cf < 4; ++cf)
    bp[cf] = hT + (size_t)(b*512 + w*64 + cf*16 + fl) * 2048 + kq*8;

  // adj staging: thread owns 2 bitmap words per 512-j chunk
  const int srow0 = tid >> 4, srow1 = 32 + (tid >> 4), stw = tid & 15;
  const int* agp0 = adj + (size_t)(b*2048 + i0 + srow0) * 2048 + stw*32;
  const int* agp1 = adj + (size_t)(b*2048 + i0 + srow1) * 2048 + stw*32;
  const int wa0 = srow0*64 + ((stw*4 + 4*srow0) & 63);
  const int wa1 = srow1*64 + ((stw*4 + 4*srow1) & 63);

  f32x4 acc[4][4];
  #pragma unroll
  for (int i = 0; i < 4; ++i)
    #pragma unroll
    for (int j = 0; j < 4; ++j) acc[i][j] = (f32x4){0.f,0.f,0.f,0.f};
  float s[4] = {0.f, 0.f, 0.f, 0.f};

  i32x4 bcur[4], bnxt[4];
  #pragma unroll
  for (int cf = 0; cf < 4; ++cf) bcur[cf] = *(const i32x4*)(bp[cf]);

  i32x4 va[16];
  #pragma unroll
  for (int q = 0; q < 8; ++q) {
    va[q]   = __builtin_nontemporal_load((const i32x4*)(agp0 + q*4));
    va[8+q] = __builtin_nontemporal_load((const i32x4*)(agp1 + q*4));
  }
  {
    unsigned int b0 = 0, b1 = 0;
    #pragma unroll
    for (int q = 0; q < 8; ++q)
      #pragma unroll
      for (int e = 0; e < 4; ++e) {
        b0 |= ((unsigned)va[q][e]   & 1u) << (q*4 + e);
        b1 |= ((unsigned)va[8+q][e] & 1u) << (q*4 + e);
      }
    *(unsigned int*)(&abits[0][0][0] + wa0) = b0;
    *(unsigned int*)(&abits[0][0][0] + wa1) = b1;
  }
  __syncthreads();

  for (int c = 0; c < 4; ++c) {
    const int cur = c & 1;
    if (c < 3) {
      const int jo = (c + 1) * 512;
      #pragma unroll
      for (int q = 0; q < 8; ++q) {
        va[q]   = __builtin_nontemporal_load((const i32x4*)(agp0 + jo + q*4));
        va[8+q] = __builtin_nontemporal_load((const i32x4*)(agp1 + jo + q*4));
      }
    }
    for (int tl = 0; tl < 16; ++tl) {
      const int t = c*16 + tl;
      if (t < 63) {
        #pragma unroll
        for (int cf = 0; cf < 4; ++cf) bnxt[cf] = *(const i32x4*)(bp[cf] + (t+1)*32);
      }
      const f32x4 ej0 = *(const f32x4*)&ejl[t*32 + kq*8];
      const f32x4 ej1 = *(const f32x4*)&ejl[t*32 + kq*8 + 4];
      const int ao = (tl*4 + kq + 4*fl) & 63;
      i32x4 af[4];
      #pragma unroll
      for (int fr = 0; fr < 4; ++fr) {
        const unsigned int byt = abits[cur][fr*16 + fl][ao];
        float p[8];
        #pragma unroll
        for (int e = 0; e < 8; ++e) {
          float ee = eir[fr] + ((e < 4) ? ej0[e] : ej1[e-4]);
          ee = fmaxf(ee, ALPHA * ee);                 // leaky in log2 domain
          const float pv = __builtin_amdgcn_exp2f(ee);
          p[e] = (byt & (1u << e)) ? pv : 0.f;
          s[fr] += p[e];
        }
        af[fr] = (i32x4){ (int)cvtpk(p[0],p[1]), (int)cvtpk(p[2],p[3]),
                          (int)cvtpk(p[4],p[5]), (int)cvtpk(p[6],p[7]) };
      }
      #pragma unroll
      for (int fr = 0; fr < 4; ++fr)
        #pragma unroll
        for (int cf = 0; cf < 4; ++cf)
          mfma_bf16_16x16x32(acc[fr][cf], af[fr], bcur[cf]);
      #pragma unroll
      for (int cf = 0; cf < 4; ++cf) bcur[cf] = bnxt[cf];
    }
    if (c < 3) {
      unsigned int b0 = 0, b1 = 0;
      #pragma unroll
      for (int q = 0; q < 8; ++q)
        #pragma unroll
        for (int e = 0; e < 4; ++e) {
          b0 |= ((unsigned)va[q][e]   & 1u) << (q*4 + e);
          b1 |= ((unsigned)va[8+q][e] & 1u) << (q*4 + e);
        }
      *(unsigned int*)(&abits[cur ^ 1][0][0] + wa0) = b0;
      *(unsigned int*)(&abits[cur ^ 1][0][0] + wa1) = b1;
    }
    __syncthreads();
  }

  // row sums: lanes sharing fl (kq=0..3) hold disjoint j-slices
  #pragma unroll
  for (int fr = 0; fr < 4; ++fr) {
    s[fr] += __shfl_xor(s[fr], 16);
    s[fr] += __shfl_xor(s[fr], 32);
  }
  if (w == 0 && kq == 0) {
    #pragma unroll
    for (int fr = 0; fr < 4; ++fr) llds[fr*16 + fl] = s[fr];
  }
  __syncthreads();
  asm volatile("s_nop 7\ns_nop 7\ns_nop 7" :::);

  #pragma unroll
  for (int fr = 0; fr < 4; ++fr) {
    const f32x4 lv = *(const f32x4*)&llds[fr*16 + kq*4];
    f32x4 inv;
    inv.x = __builtin_amdgcn_rcpf(lv.x); inv.y = __builtin_amdgcn_rcpf(lv.y);
    inv.z = __builtin_amdgcn_rcpf(lv.z); inv.w = __builtin_amdgcn_rcpf(lv.w);
    #pragma unroll
    for (int cf = 0; cf < 4; ++cf) {
      const int f = w*64 + cf*16 + fl;
      unsigned short* cp = C1 + (size_t)(b*2048 + i0 + fr*16 + kq*4) * 512 + f;
      cp[0]    = f2bf(acc[fr][cf].x * inv.x);
      cp[512]  = f2bf(acc[fr][cf].y * inv.y);
      cp[1024] = f2bf(acc[fr][cf].z * inv.z);
      cp[1536] = f2bf(acc[fr][cf].w * inv.w);
    }
  }
}

// ---- Kernel D: out = elu(C1 @ W)  (B-frags from wt[f2][f1]) ------------------------------
// 256 blocks x 512 thr, no LDS, no barriers; A/B frags straight from L2 with depth-1 prefetch.
__global__ __launch_bounds__(512, 2) void k_gemm2(const unsigned short* __restrict__ C1,
                                                  const unsigned short* __restrict__ wt,
                                                  float* __restrict__ out) {
  const int tid = threadIdx.x;
  const int w = tid >> 6, l = tid & 63;
  const int fl = l & 15, kq = l >> 4;
  const int row0 = (blockIdx.x & 7) * 2048 + (blockIdx.x >> 3) * 64;

  const unsigned short* ap[4];
  const unsigned short* bp[4];
  #pragma unroll
  for (int fr = 0; fr < 4; ++fr) ap[fr] = C1 + (size_t)(row0 + fr*16 + fl)*512 + kq*8;
  #pragma unroll
  for (int cf = 0; cf < 4; ++cf) bp[cf] = wt + (size_t)(w*64 + cf*16 + fl)*512 + kq*8;

  f32x4 acc[4][4];
  #pragma unroll
  for (int i = 0; i < 4; ++i)
    #pragma unroll
    for (int j = 0; j < 4; ++j) acc[i][j] = (f32x4){0.f,0.f,0.f,0.f};

  i32x4 ac[4], bc[4], an[4], bn[4];
  #pragma unroll
  for (int x = 0; x < 4; ++x) { ac[x] = *(const i32x4*)(ap[x]); bc[x] = *(const i32x4*)(bp[x]); }

  for (int sI = 0; sI < 16; ++sI) {
    const int sn = (sI < 15) ? sI + 1 : 15;
    #pragma unroll
    for (int x = 0; x < 4; ++x) {
      an[x] = *(const i32x4*)(ap[x] + sn*32);
      bn[x] = *(const i32x4*)(bp[x] + sn*32);
    }
    #pragma unroll
    for (int fr = 0; fr < 4; ++fr)
      #pragma unroll
      for (int cf = 0; cf < 4; ++cf)
        mfma_bf16_16x16x32(acc[fr][cf], ac[fr], bc[cf]);
    #pragma unroll
    for (int x = 0; x < 4; ++x) { ac[x] = an[x]; bc[x] = bn[x]; }
  }

  asm volatile("s_nop 7\ns_nop 7\ns_nop 7" :::);
  #pragma unroll
  for (int fr = 0; fr < 4; ++fr)
    #pragma unroll
    for (int cf = 0; cf < 4; ++cf) {
      const int f = w*64 + cf*16 + fl;
      float* op = out + (size_t)(row0 + fr*16 + kq*4) * 512 + f;
      const f32x4 v = acc[fr][cf];
      float o0 = v.x > 0.f ? v.x : __builtin_amdgcn_exp2f(v.x * LOG2E) - 1.f;
      float o1 = v.y > 0.f ? v.y : __builtin_amdgcn_exp2f(v.y * LOG2E) - 1.f;
      float o2 = v.z > 0.f ? v.z : __builtin_amdgcn_exp2f(v.z * LOG2E) - 1.f;
      float o3 = v.w > 0.f ? v.w : __builtin_amdgcn_exp2f(v.w * LOG2E) - 1.f;
      __builtin_nontemporal_store(o0, op);
      __builtin_nontemporal_store(o1, op + 512);
      __builtin_nontemporal_store(o2, op + 1024);
      __builtin_nontemporal_store(o3, op + 1536);
    }
}

extern "C" void kernel_launch(void* const* d_in, const int* in_sizes, int n_in,
                              void* d_out, int out_size, void* d_ws, size_t ws_size,
                              hipStream_t stream) {
  const float* h  = (const float*)d_in[0];
  const int*  adj = (const int*)d_in[1];
  const float* W  = (const float*)d_in[2];
  const float* a  = (const float*)d_in[3];
  float* out = (float*)d_out;
  char* ws = (char*)d_ws;
  unsigned short* wt = (unsigned short*)(ws);                        // 512*512*2      = 524288
  unsigned short* hT = (unsigned short*)(ws + 524288);               // 8*512*2048*2   = 16777216
  unsigned short* C1 = (unsigned short*)(ws + 17301504);             // 16384*512*2    = 16777216
  float* ei = (float*)(ws + 34078720);                               // 16384*4
  float* ej = (float*)(ws + 34144256);                               // 16384*4
  float* v1 = (float*)(ws + 34209792);                               // 512*4
  float* v2 = (float*)(ws + 34211840);                               // 512*4  (total ~34.2 MB)

  hipLaunchKernelGGL(k_setup, dim3(416),  dim3(256), 0, stream, W, a, wt, v1, v2, ei);
  hipLaunchKernelGGL(k_prep,  dim3(8192), dim3(256), 0, stream, h, v1, v2, hT, ei, ej);
  hipLaunchKernelGGL(k_attn,  dim3(256),  dim3(512), 0, stream, adj, hT, ei, ej, C1);
  hipLaunchKernelGGL(k_gemm2, dim3(256),  dim3(512), 0, stream, C1, wt, out);
}

// Round 7
// 362.745 us; speedup vs baseline: 1.0762x; 1.0762x over previous
//
#include <hip/hip_runtime.h>
#include <hip/hip_bf16.h>

#define ALPHA 0.2f
#define LOG2E 1.44269504088896340736f

typedef float  f32x4 __attribute__((ext_vector_type(4)));
typedef float  f32x2 __attribute__((ext_vector_type(2)));
typedef int    i32x4 __attribute__((ext_vector_type(4)));
typedef int    i32x2 __attribute__((ext_vector_type(2)));
typedef unsigned int u32x2 __attribute__((ext_vector_type(2)));

static __device__ __forceinline__ void mfma_bf16_16x16x32(f32x4& c, i32x4 a, i32x4 b) {
  asm("v_mfma_f32_16x16x32_bf16 %0, %1, %2, %0" : "+v"(c) : "v"(a), "v"(b));
}
static __device__ __forceinline__ unsigned short f2bf(float x) {
  __hip_bfloat16 b = __float2bfloat16(x);
  return *reinterpret_cast<unsigned short*>(&b);
}
static __device__ __forceinline__ unsigned int cvtpk(float lo, float hi) {
  unsigned int r;
  asm("v_cvt_pk_bf16_f32 %0, %1, %2" : "=v"(r) : "v"(lo), "v"(hi));
  return r;
}
static __device__ __forceinline__ float dot4(f32x4 a, f32x4 b) {
  return a.x*b.x + a.y*b.y + a.z*b.z + a.w*b.w;
}

// ---- Kernel A: wt[f][k]=bf16(W[k][f]); v1=log2e*(W@a1), v2=log2e*(W@a2); zero ei/ej ----
__global__ __launch_bounds__(256) void k_setup(const float* __restrict__ W, const float* __restrict__ a,
                                               unsigned short* __restrict__ wt,
                                               float* __restrict__ v1, float* __restrict__ v2,
                                               float* __restrict__ eiej) {
  const int bid = blockIdx.x, tid = threadIdx.x;
  __shared__ float S[32][33];
  if (bid < 256) {               // transpose W -> wt (bf16)
    const int k0 = (bid >> 4) * 32, f0 = (bid & 15) * 32;
    const int r = tid >> 5, c = tid & 31;
    #pragma unroll
    for (int rr = r; rr < 32; rr += 8) S[rr][c] = W[(size_t)(k0 + rr) * 512 + f0 + c];
    __syncthreads();
    #pragma unroll
    for (int rr = r; rr < 32; rr += 8) wt[(size_t)(f0 + rr) * 512 + k0 + c] = f2bf(S[c][rr]);
  } else if (bid < 384) {        // v1/v2
    const int kk = (bid - 256) * 4 + (tid >> 6);
    const int l = tid & 63;
    const float* wr = W + (size_t)kk * 512 + l * 8;
    f32x4 w0 = *(const f32x4*)(wr),            w1 = *(const f32x4*)(wr + 4);
    f32x4 p0 = *(const f32x4*)(a + l*8),       p1 = *(const f32x4*)(a + l*8 + 4);
    f32x4 q0 = *(const f32x4*)(a + 512 + l*8), q1 = *(const f32x4*)(a + 512 + l*8 + 4);
    float s1 = dot4(w0,p0) + dot4(w1,p1);
    float s2 = dot4(w0,q0) + dot4(w1,q1);
    #pragma unroll
    for (int off = 1; off < 64; off <<= 1) { s1 += __shfl_xor(s1, off); s2 += __shfl_xor(s2, off); }
    if (l == 0) { v1[kk] = s1 * LOG2E; v2[kk] = s2 * LOG2E; }
  } else {                       // zero ei+ej
    const int idx = (bid - 384) * 1024 + tid * 4;
    *(f32x4*)(eiej + idx) = (f32x4){0.f,0.f,0.f,0.f};
  }
}

// ---- Kernel B: hT[b][f][n]=bf16(h[b][n][f]); ei/ej via fused dots + atomicAdd -----------
__global__ __launch_bounds__(256) void k_prep(const float* __restrict__ h,
                                              const float* __restrict__ v1, const float* __restrict__ v2,
                                              unsigned short* __restrict__ hT,
                                              float* __restrict__ ei, float* __restrict__ ej) {
  const int bid = blockIdx.x, tid = threadIdx.x;
  const int ft = bid & 15, nt = (bid >> 4) & 63, b = bid >> 10;
  __shared__ __align__(16) float S[32][36];

  const int n_loc = tid >> 3, fq = (tid & 7) * 4;
  const f32x4 v = __builtin_nontemporal_load(
      (const f32x4*)(h + (size_t)(b*2048 + nt*32 + n_loc)*512 + ft*32 + fq));
  *(f32x4*)&S[n_loc][fq] = v;

  const f32x4 a1 = *(const f32x4*)(v1 + ft*32 + fq);
  const f32x4 a2 = *(const f32x4*)(v2 + ft*32 + fq);
  float s1 = dot4(v, a1), s2 = dot4(v, a2);
  #pragma unroll
  for (int off = 1; off < 8; off <<= 1) { s1 += __shfl_xor(s1, off); s2 += __shfl_xor(s2, off); }
  if ((tid & 7) == 0) {
    atomicAdd(&ei[b*2048 + nt*32 + n_loc], s1);
    atomicAdd(&ej[b*2048 + nt*32 + n_loc], s2);
  }
  __syncthreads();

  const int f_loc = tid >> 3, nq = (tid & 7) * 4;
  u32x2 pk;
  pk.x = cvtpk(S[nq+0][f_loc], S[nq+1][f_loc]);
  pk.y = cvtpk(S[nq+2][f_loc], S[nq+3][f_loc]);
  *(u32x2*)(hT + (size_t)(b*512 + ft*32 + f_loc)*2048 + nt*32 + nq) = pk;
}

// ---- Kernel C: C1[b][i][f] = bf16( (softmax-att @ h)[i][f] ) -----------------------------
// 512 blocks (b=bid&7 -> XCD-local hT slice; i-tile 32), 512 thr = 8 waves, 2 blocks/CU.
// Super-step = 128 j's: each wave computes P for its 4 i-rows ONCE -> swizzled LDS (dbuf),
// 1 barrier/super-step (17 total). MFMA: per super-step 4 k-steps x 2fr x 4cf per wave.
// adj depth-2 register prefetch (nontemporal); B-frags rolling depth-1 from L2-resident hT.
__global__ __launch_bounds__(512, 4) void k_attn(const int* __restrict__ adj,
                                                 const unsigned short* __restrict__ hT,
                                                 const float* __restrict__ ei, const float* __restrict__ ej,
                                                 unsigned short* __restrict__ C1) {
  const int tid = threadIdx.x;
  const int w = tid >> 6, l = tid & 63;
  const int fl = l & 15, kq = l >> 4;
  const int b = blockIdx.x & 7;
  const int i0 = (blockIdx.x >> 3) * 32;

  __shared__ __align__(16) unsigned short Plds[2][4096];   // [32 rows][128 j] bf16, XOR-swizzled
  __shared__ __align__(16) float ejl[2048];
  __shared__ __align__(16) float llds[32];

  // stage ej -> LDS
  *(f32x4*)&ejl[tid*4] = *(const f32x4*)(ej + b*2048 + tid*4);

  // ---- P-producer role: row prow, j-slice [pj, pj+8) of each 128-j super-step
  const int prow = w*4 + (l >> 4);              // 0..31
  const int pj   = (l & 15) * 8;                // 0..120
  const float eir = ei[b*2048 + i0 + prow];
  const int* aptr = adj + ((size_t)(b*2048 + i0 + prow) << 11) + pj;
  const int wboff = prow*256 + ((pj*2) ^ ((prow & 7) << 4));  // swizzled write byte offset

  // ---- MFMA-consumer role
  const unsigned short* bp[4];
  #pragma unroll
  for (int cf = 0; cf < 4; ++cf)
    bp[cf] = hT + (size_t)(b*512 + w*64 + cf*16 + fl) * 2048 + kq*8;
  const int zz = ((kq ^ (fl & 7)) << 4);        // A-frag swizzle lane constant
  const int arow0 = fl * 256, arow1 = (16 + fl) * 256;

  f32x4 acc[2][4];
  #pragma unroll
  for (int i = 0; i < 2; ++i)
    #pragma unroll
    for (int j = 0; j < 4; ++j) acc[i][j] = (f32x4){0.f,0.f,0.f,0.f};
  float sum = 0.f;

  i32x4 bcur[4];
  #pragma unroll
  for (int cf = 0; cf < 4; ++cf) bcur[cf] = *(const i32x4*)(bp[cf]);

  // adj prefetch: pfa -> next-even target, pfb -> next-odd target
  i32x4 pfa0 = __builtin_nontemporal_load((const i32x4*)(aptr));
  i32x4 pfa1 = __builtin_nontemporal_load((const i32x4*)(aptr + 4));
  i32x4 pfb0 = __builtin_nontemporal_load((const i32x4*)(aptr + 128));
  i32x4 pfb1 = __builtin_nontemporal_load((const i32x4*)(aptr + 128 + 4));

#define P_PHASE(BUFI, S, A0, A1) do {                                          \
    const f32x4 e0 = *(const f32x4*)&ejl[(S)*128 + pj];                        \
    const f32x4 e1 = *(const f32x4*)&ejl[(S)*128 + pj + 4];                    \
    float p[8];                                                                \
    _Pragma("unroll")                                                          \
    for (int e = 0; e < 8; ++e) {                                              \
      float x = eir + ((e < 4) ? e0[e] : e1[e-4]);                             \
      x = fmaxf(x, ALPHA * x);                                                 \
      const float pv = __builtin_amdgcn_exp2f(x);                              \
      const int av = (e < 4) ? (A0)[e] : (A1)[e-4];                            \
      p[e] = av ? pv : 0.f;                                                    \
      sum += p[e];                                                             \
    }                                                                          \
    i32x4 pk;                                                                  \
    pk.x = (int)cvtpk(p[0],p[1]); pk.y = (int)cvtpk(p[2],p[3]);                \
    pk.z = (int)cvtpk(p[4],p[5]); pk.w = (int)cvtpk(p[6],p[7]);                \
    *(i32x4*)((char*)&Plds[BUFI][0] + wboff) = pk;                             \
  } while (0)

#define MFMA_STEP(BUFI, S) do {                                                \
    const char* pb = (const char*)&Plds[BUFI][0];                              \
    _Pragma("unroll")                                                          \
    for (int kk = 0; kk < 4; ++kk) {                                           \
      const int t = (S)*4 + kk;                                                \
      const int tn = (t < 63) ? t + 1 : 63;                                    \
      i32x4 bnxt[4];                                                           \
      _Pragma("unroll")                                                        \
      for (int cf = 0; cf < 4; ++cf) bnxt[cf] = *(const i32x4*)(bp[cf] + tn*32); \
      const i32x4 af0 = *(const i32x4*)(pb + arow0 + ((kk << 6) ^ zz));        \
      const i32x4 af1 = *(const i32x4*)(pb + arow1 + ((kk << 6) ^ zz));        \
      _Pragma("unroll")                                                        \
      for (int cf = 0; cf < 4; ++cf) {                                         \
        mfma_bf16_16x16x32(acc[0][cf], af0, bcur[cf]);                         \
        mfma_bf16_16x16x32(acc[1][cf], af1, bcur[cf]);                         \
      }                                                                        \
      _Pragma("unroll")                                                        \
      for (int cf = 0; cf < 4; ++cf) bcur[cf] = bnxt[cf];                      \
    }                                                                          \
  } while (0)

  __syncthreads();                    // ejl ready
  P_PHASE(0, 0, pfa0, pfa1);          // P(0)
  pfa0 = __builtin_nontemporal_load((const i32x4*)(aptr + 2*128));
  pfa1 = __builtin_nontemporal_load((const i32x4*)(aptr + 2*128 + 4));
  __syncthreads();                    // buf0 ready

  for (int ss = 0; ss < 8; ++ss) {
    const int s0 = ss*2, s1 = ss*2 + 1;
    MFMA_STEP(0, s0);
    P_PHASE(1, s0 + 1, pfb0, pfb1);
    if (s0 + 3 < 16) {
      pfb0 = __builtin_nontemporal_load((const i32x4*)(aptr + (s0+3)*128));
      pfb1 = __builtin_nontemporal_load((const i32x4*)(aptr + (s0+3)*128 + 4));
    }
    __syncthreads();
    MFMA_STEP(1, s1);
    if (s1 < 15) {
      P_PHASE(0, s1 + 1, pfa0, pfa1);
      if (s1 + 3 < 16) {
        pfa0 = __builtin_nontemporal_load((const i32x4*)(aptr + (s1+3)*128));
        pfa1 = __builtin_nontemporal_load((const i32x4*)(aptr + (s1+3)*128 + 4));
      }
    }
    __syncthreads();
  }
#undef P_PHASE
#undef MFMA_STEP

  // row sums: 16 lanes (l&15) share row prow
  sum += __shfl_xor(sum, 1);
  sum += __shfl_xor(sum, 2);
  sum += __shfl_xor(sum, 4);
  sum += __shfl_xor(sum, 8);
  if ((l & 15) == 0) llds[prow] = sum;
  __syncthreads();
  asm volatile("s_nop 7\ns_nop 7\ns_nop 7" :::);

  #pragma unroll
  for (int fr = 0; fr < 2; ++fr) {
    const f32x4 lv = *(const f32x4*)&llds[fr*16 + kq*4];
    f32x4 inv;
    inv.x = __builtin_amdgcn_rcpf(lv.x); inv.y = __builtin_amdgcn_rcpf(lv.y);
    inv.z = __builtin_amdgcn_rcpf(lv.z); inv.w = __builtin_amdgcn_rcpf(lv.w);
    #pragma unroll
    for (int cf = 0; cf < 4; ++cf) {
      const int f = w*64 + cf*16 + fl;
      unsigned short* cp = C1 + (size_t)(b*2048 + i0 + fr*16 + kq*4) * 512 + f;
      cp[0]    = f2bf(acc[fr][cf].x * inv.x);
      cp[512]  = f2bf(acc[fr][cf].y * inv.y);
      cp[1024] = f2bf(acc[fr][cf].z * inv.z);
      cp[1536] = f2bf(acc[fr][cf].w * inv.w);
    }
  }
}

// ---- Kernel D: out = elu(C1 @ W)  (B-frags from wt[f2][f1]) ------------------------------
__global__ __launch_bounds__(512, 2) void k_gemm2(const unsigned short* __restrict__ C1,
                                                  const unsigned short* __restrict__ wt,
                                                  float* __restrict__ out) {
  const int tid = threadIdx.x;
  const int w = tid >> 6, l = tid & 63;
  const int fl = l & 15, kq = l >> 4;
  const int row0 = (blockIdx.x & 7) * 2048 + (blockIdx.x >> 3) * 64;

  const unsigned short* ap[4];
  const unsigned short* bp[4];
  #pragma unroll
  for (int fr = 0; fr < 4; ++fr) ap[fr] = C1 + (size_t)(row0 + fr*16 + fl)*512 + kq*8;
  #pragma unroll
  for (int cf = 0; cf < 4; ++cf) bp[cf] = wt + (size_t)(w*64 + cf*16 + fl)*512 + kq*8;

  f32x4 acc[4][4];
  #pragma unroll
  for (int i = 0; i < 4; ++i)
    #pragma unroll
    for (int j = 0; j < 4; ++j) acc[i][j] = (f32x4){0.f,0.f,0.f,0.f};

  i32x4 ac[4], bc[4], an[4], bn[4];
  #pragma unroll
  for (int x = 0; x < 4; ++x) { ac[x] = *(const i32x4*)(ap[x]); bc[x] = *(const i32x4*)(bp[x]); }

  for (int sI = 0; sI < 16; ++sI) {
    const int sn = (sI < 15) ? sI + 1 : 15;
    #pragma unroll
    for (int x = 0; x < 4; ++x) {
      an[x] = *(const i32x4*)(ap[x] + sn*32);
      bn[x] = *(const i32x4*)(bp[x] + sn*32);
    }
    #pragma unroll
    for (int fr = 0; fr < 4; ++fr)
      #pragma unroll
      for (int cf = 0; cf < 4; ++cf)
        mfma_bf16_16x16x32(acc[fr][cf], ac[fr], bc[cf]);
    #pragma unroll
    for (int x = 0; x < 4; ++x) { ac[x] = an[x]; bc[x] = bn[x]; }
  }

  asm volatile("s_nop 7\ns_nop 7\ns_nop 7" :::);
  #pragma unroll
  for (int fr = 0; fr < 4; ++fr)
    #pragma unroll
    for (int cf = 0; cf < 4; ++cf) {
      const int f = w*64 + cf*16 + fl;
      float* op = out + (size_t)(row0 + fr*16 + kq*4) * 512 + f;
      const f32x4 v = acc[fr][cf];
      float o0 = v.x > 0.f ? v.x : __builtin_amdgcn_exp2f(v.x * LOG2E) - 1.f;
      float o1 = v.y > 0.f ? v.y : __builtin_amdgcn_exp2f(v.y * LOG2E) - 1.f;
      float o2 = v.z > 0.f ? v.z : __builtin_amdgcn_exp2f(v.z * LOG2E) - 1.f;
      float o3 = v.w > 0.f ? v.w : __builtin_amdgcn_exp2f(v.w * LOG2E) - 1.f;
      __builtin_nontemporal_store(o0, op);
      __builtin_nontemporal_store(o1, op + 512);
      __builtin_nontemporal_store(o2, op + 1024);
      __builtin_nontemporal_store(o3, op + 1536);
    }
}

extern "C" void kernel_launch(void* const* d_in, const int* in_sizes, int n_in,
                              void* d_out, int out_size, void* d_ws, size_t ws_size,
                              hipStream_t stream) {
  const float* h  = (const float*)d_in[0];
  const int*  adj = (const int*)d_in[1];
  const float* W  = (const float*)d_in[2];
  const float* a  = (const float*)d_in[3];
  float* out = (float*)d_out;
  char* ws = (char*)d_ws;
  unsigned short* wt = (unsigned short*)(ws);                        // 512*512*2      = 524288
  unsigned short* hT = (unsigned short*)(ws + 524288);               // 8*512*2048*2   = 16777216
  unsigned short* C1 = (unsigned short*)(ws + 17301504);             // 16384*512*2    = 16777216
  float* ei = (float*)(ws + 34078720);                               // 16384*4
  float* ej = (float*)(ws + 34144256);                               // 16384*4
  float* v1 = (float*)(ws + 34209792);                               // 512*4
  float* v2 = (float*)(ws + 34211840);                               // 512*4

  hipLaunchKernelGGL(k_setup, dim3(416),  dim3(256), 0, stream, W, a, wt, v1, v2, ei);
  hipLaunchKernelGGL(k_prep,  dim3(8192), dim3(256), 0, stream, h, v1, v2, hT, ei, ej);
  hipLaunchKernelGGL(k_attn,  dim3(512),  dim3(512), 0, stream, adj, hT, ei, ej, C1);
  hipLaunchKernelGGL(k_gemm2, dim3(256),  dim3(512), 0, stream, C1, wt, out);
}

// Round 13
// 324.857 us; speedup vs baseline: 1.2017x; 1.1166x over previous
//
#include <hip/hip_runtime.h>
#include <hip/hip_bf16.h>

#define ALPHA 0.2f
#define LOG2E 1.44269504088896340736f

typedef float  f32x4 __attribute__((ext_vector_type(4)));
typedef float  f32x2 __attribute__((ext_vector_type(2)));
typedef int    i32x4 __attribute__((ext_vector_type(4)));
typedef int    i32x2 __attribute__((ext_vector_type(2)));
typedef unsigned int u32x2 __attribute__((ext_vector_type(2)));

static __device__ __forceinline__ void mfma_bf16_16x16x32(f32x4& c, i32x4 a, i32x4 b) {
  asm("v_mfma_f32_16x16x32_bf16 %0, %1, %2, %0" : "+v"(c) : "v"(a), "v"(b));
}
static __device__ __forceinline__ unsigned short f2bf(float x) {
  __hip_bfloat16 b = __float2bfloat16(x);
  return *reinterpret_cast<unsigned short*>(&b);
}
static __device__ __forceinline__ unsigned int cvtpk(float lo, float hi) {
  unsigned int r;
  asm("v_cvt_pk_bf16_f32 %0, %1, %2" : "=v"(r) : "v"(lo), "v"(hi));
  return r;
}
static __device__ __forceinline__ float dot4(f32x4 a, f32x4 b) {
  return a.x*b.x + a.y*b.y + a.z*b.z + a.w*b.w;
}

// ---- Kernel A: wt[f][k]=bf16(W[k][f]); v1=log2e*(W@a1), v2=log2e*(W@a2); zero ei/ej ----
__global__ __launch_bounds__(256) void k_setup(const float* __restrict__ W, const float* __restrict__ a,
                                               unsigned short* __restrict__ wt,
                                               float* __restrict__ v1, float* __restrict__ v2,
                                               float* __restrict__ eiej) {
  const int bid = blockIdx.x, tid = threadIdx.x;
  __shared__ float S[32][33];
  if (bid < 256) {               // transpose W -> wt (bf16)
    const int k0 = (bid >> 4) * 32, f0 = (bid & 15) * 32;
    const int r = tid >> 5, c = tid & 31;
    #pragma unroll
    for (int rr = r; rr < 32; rr += 8) S[rr][c] = W[(size_t)(k0 + rr) * 512 + f0 + c];
    __syncthreads();
    #pragma unroll
    for (int rr = r; rr < 32; rr += 8) wt[(size_t)(f0 + rr) * 512 + k0 + c] = f2bf(S[c][rr]);
  } else if (bid < 384) {        // v1/v2
    const int kk = (bid - 256) * 4 + (tid >> 6);
    const int l = tid & 63;
    const float* wr = W + (size_t)kk * 512 + l * 8;
    f32x4 w0 = *(const f32x4*)(wr),            w1 = *(const f32x4*)(wr + 4);
    f32x4 p0 = *(const f32x4*)(a + l*8),       p1 = *(const f32x4*)(a + l*8 + 4);
    f32x4 q0 = *(const f32x4*)(a + 512 + l*8), q1 = *(const f32x4*)(a + 512 + l*8 + 4);
    float s1 = dot4(w0,p0) + dot4(w1,p1);
    float s2 = dot4(w0,q0) + dot4(w1,q1);
    #pragma unroll
    for (int off = 1; off < 64; off <<= 1) { s1 += __shfl_xor(s1, off); s2 += __shfl_xor(s2, off); }
    if (l == 0) { v1[kk] = s1 * LOG2E; v2[kk] = s2 * LOG2E; }
  } else {                       // zero ei+ej
    const int idx = (bid - 384) * 1024 + tid * 4;
    *(f32x4*)(eiej + idx) = (f32x4){0.f,0.f,0.f,0.f};
  }
}

// ---- Kernel P: pack adj (0/1 ints) -> bitmask, 16 j per ushort. 134MB -> 4MB. ----------
__global__ __launch_bounds__(256) void k_pack(const int* __restrict__ adj,
                                              unsigned short* __restrict__ adjb) {
  const size_t g = (size_t)blockIdx.x * 256 + threadIdx.x;    // 2M ushorts
  const int* p = adj + g * 16;
  const i32x4 v0 = __builtin_nontemporal_load((const i32x4*)(p));
  const i32x4 v1 = __builtin_nontemporal_load((const i32x4*)(p + 4));
  const i32x4 v2 = __builtin_nontemporal_load((const i32x4*)(p + 8));
  const i32x4 v3 = __builtin_nontemporal_load((const i32x4*)(p + 12));
  unsigned int m = 0;
  #pragma unroll
  for (int e = 0; e < 4; ++e) {
    m |= ((unsigned)v0[e] & 1u) << e;
    m |= ((unsigned)v1[e] & 1u) << (4 + e);
    m |= ((unsigned)v2[e] & 1u) << (8 + e);
    m |= ((unsigned)v3[e] & 1u) << (12 + e);
  }
  adjb[g] = (unsigned short)m;
}

// ---- Kernel B: hT[b][f][n]=bf16(h[b][n][f]); ei/ej via fused dots + atomicAdd -----------
__global__ __launch_bounds__(256) void k_prep(const float* __restrict__ h,
                                              const float* __restrict__ v1, const float* __restrict__ v2,
                                              unsigned short* __restrict__ hT,
                                              float* __restrict__ ei, float* __restrict__ ej) {
  const int bid = blockIdx.x, tid = threadIdx.x;
  const int ft = bid & 15, nt = (bid >> 4) & 63, b = bid >> 10;
  __shared__ __align__(16) float S[32][36];

  const int n_loc = tid >> 3, fq = (tid & 7) * 4;
  const f32x4 v = __builtin_nontemporal_load(
      (const f32x4*)(h + (size_t)(b*2048 + nt*32 + n_loc)*512 + ft*32 + fq));
  *(f32x4*)&S[n_loc][fq] = v;

  const f32x4 a1 = *(const f32x4*)(v1 + ft*32 + fq);
  const f32x4 a2 = *(const f32x4*)(v2 + ft*32 + fq);
  float s1 = dot4(v, a1), s2 = dot4(v, a2);
  #pragma unroll
  for (int off = 1; off < 8; off <<= 1) { s1 += __shfl_xor(s1, off); s2 += __shfl_xor(s2, off); }
  if ((tid & 7) == 0) {
    atomicAdd(&ei[b*2048 + nt*32 + n_loc], s1);
    atomicAdd(&ej[b*2048 + nt*32 + n_loc], s2);
  }
  __syncthreads();

  const int f_loc = tid >> 3, nq = (tid & 7) * 4;
  u32x2 pk;
  pk.x = cvtpk(S[nq+0][f_loc], S[nq+1][f_loc]);
  pk.y = cvtpk(S[nq+2][f_loc], S[nq+3][f_loc]);
  *(u32x2*)(hT + (size_t)(b*512 + ft*32 + f_loc)*2048 + nt*32 + nq) = pk;
}

// ---- Kernel C: C1[b][i][f] = bf16( (softmax-att @ h)[i][f] ) -----------------------------
// 256 blocks = 16 i-tiles(128) x 8 b x 2 f-halves; 1024 thr = 16 waves (2m x 8f), 1 block/CU.
// P[128][128] bf16 (swizzled, dbuf 64KB LDS) produced once per block per super-step;
// adj read from 4MB L2-resident bitmask (k_pack). B-frags depth-1 from L2-resident hT half.
__global__ __launch_bounds__(1024, 4) void k_attn(const unsigned short* __restrict__ adjb,
                                                  const unsigned short* __restrict__ hT,
                                                  const float* __restrict__ ei, const float* __restrict__ ej,
                                                  unsigned short* __restrict__ C1) {
  const int tid = threadIdx.x;
  const int w = tid >> 6, l = tid & 63;
  const int fl = l & 15, kq = l >> 4;
  const int bid = blockIdx.x;
  const int fh = bid & 1;
  const int b  = (bid >> 1) & 7;
  const int i0 = (bid >> 4) * 128;

  __shared__ __align__(16) unsigned short Plds[2][16384];   // [128 rows][128 j] bf16, swizzled
  __shared__ __align__(16) float ejl[2048];
  __shared__ __align__(16) float llds[128];

  if (tid < 512) *(f32x4*)&ejl[tid*4] = *(const f32x4*)(ej + b*2048 + tid*4);

  // ---- P-producer role: row pr, 16-j slice js of each 128-j super-step
  const int pr = tid >> 3;                     // 0..127
  const int js = (tid & 7) * 16;               // 0..112
  const float eir = ei[b*2048 + i0 + pr];
  const char* abp = (const char*)adjb + (size_t)(b*2048 + i0 + pr) * 256 + (tid & 7) * 2;
  const int swp = (pr & 7) << 4;
  const int wb0 = pr*256 + ((js*2)      ^ swp);
  const int wb1 = pr*256 + ((js*2 + 16) ^ swp);

  // ---- MFMA-consumer role: wave (mw, fw) = 64 rows x 32 f
  const int mw = w >> 3, fw = w & 7;
  const unsigned short* bp[2];
  #pragma unroll
  for (int cf = 0; cf < 2; ++cf)
    bp[cf] = hT + (size_t)(b*512 + fh*256 + fw*32 + cf*16 + fl) * 2048 + kq*8;
  const int swz = (fl & 7) << 4;
  int abase[4];
  #pragma unroll
  for (int mf = 0; mf < 4; ++mf) abase[mf] = (mw*64 + mf*16 + fl) * 256;

  f32x4 acc[4][2];
  #pragma unroll
  for (int i = 0; i < 4; ++i)
    #pragma unroll
    for (int j = 0; j < 2; ++j) acc[i][j] = (f32x4){0.f,0.f,0.f,0.f};
  float sum = 0.f;

  i32x4 bcur[2];
  #pragma unroll
  for (int cf = 0; cf < 2; ++cf) bcur[cf] = *(const i32x4*)(bp[cf]);

#define P_PHASE(BUFI, S, BITS) do {                                            \
    const f32x4 ev0 = *(const f32x4*)&ejl[(S)*128 + js];                       \
    const f32x4 ev1 = *(const f32x4*)&ejl[(S)*128 + js + 4];                   \
    const f32x4 ev2 = *(const f32x4*)&ejl[(S)*128 + js + 8];                   \
    const f32x4 ev3 = *(const f32x4*)&ejl[(S)*128 + js + 12];                  \
    float p[16];                                                               \
    _Pragma("unroll")                                                          \
    for (int e = 0; e < 16; ++e) {                                             \
      const float ejv = (e < 4) ? ev0[e] : (e < 8) ? ev1[e-4]                  \
                       : (e < 12) ? ev2[e-8] : ev3[e-12];                      \
      float x = eir + ejv;                                                     \
      x = fmaxf(x, ALPHA * x);                   /* leaky in log2 domain */    \
      const float pv = __builtin_amdgcn_exp2f(x);                              \
      p[e] = (((BITS) >> e) & 1u) ? pv : 0.f;                                  \
      sum += p[e];                                                             \
    }                                                                          \
    i32x4 pk0, pk1;                                                            \
    pk0.x = (int)cvtpk(p[0],p[1]);   pk0.y = (int)cvtpk(p[2],p[3]);            \
    pk0.z = (int)cvtpk(p[4],p[5]);   pk0.w = (int)cvtpk(p[6],p[7]);            \
    pk1.x = (int)cvtpk(p[8],p[9]);   pk1.y = (int)cvtpk(p[10],p[11]);          \
    pk1.z = (int)cvtpk(p[12],p[13]); pk1.w = (int)cvtpk(p[14],p[15]);          \
    *(i32x4*)((char*)&Plds[BUFI][0] + wb0) = pk0;                              \
    *(i32x4*)((char*)&Plds[BUFI][0] + wb1) = pk1;                              \
  } while (0)

#define MFMA_STEP(BUFI, S) do {                                                \
    const char* pb = (const char*)&Plds[BUFI][0];                              \
    _Pragma("unroll")                                                          \
    for (int kk = 0; kk < 4; ++kk) {                                           \
      const int t = (S)*4 + kk;                                                \
      const int tn = (t < 63) ? t + 1 : 63;                                    \
      i32x4 bnxt[2];                                                           \
      _Pragma("unroll")                                                        \
      for (int cf = 0; cf < 2; ++cf) bnxt[cf] = *(const i32x4*)(bp[cf] + tn*32); \
      i32x4 af[4];                                                             \
      _Pragma("unroll")                                                        \
      for (int mf = 0; mf < 4; ++mf)                                           \
        af[mf] = *(const i32x4*)(pb + abase[mf] + ((kk*64 + kq*16) ^ swz));    \
      _Pragma("unroll")                                                        \
      for (int mf = 0; mf < 4; ++mf)                                           \
        _Pragma("unroll")                                                      \
        for (int cf = 0; cf < 2; ++cf)                                         \
          mfma_bf16_16x16x32(acc[mf][cf], af[mf], bcur[cf]);                   \
      _Pragma("unroll")                                                        \
      for (int cf = 0; cf < 2; ++cf) bcur[cf] = bnxt[cf];                      \
    }                                                                          \
  } while (0)

  unsigned int bits = *(const unsigned short*)(abp);            // ss=0
  __syncthreads();                     // ejl ready
  P_PHASE(0, 0, bits);
  bits = *(const unsigned short*)(abp + 16);                    // ss=1
  __syncthreads();                     // buf0 ready

  for (int ssi = 0; ssi < 16; ++ssi) {
    const int cur = ssi & 1;
    MFMA_STEP(cur, ssi);
    if (ssi < 15) {
      const int sspf = (ssi + 2 < 16) ? ssi + 2 : 15;
      const unsigned int bn = *(const unsigned short*)(abp + sspf*16);
      P_PHASE(cur ^ 1, ssi + 1, bits);
      bits = bn;
    }
    __syncthreads();
  }
#undef P_PHASE
#undef MFMA_STEP

  // row sums: 8 lanes (tid&7) share row pr
  sum += __shfl_xor(sum, 1);
  sum += __shfl_xor(sum, 2);
  sum += __shfl_xor(sum, 4);
  if ((tid & 7) == 0) llds[pr] = sum;
  __syncthreads();
  asm volatile("s_nop 7\ns_nop 7\ns_nop 7" :::);

  #pragma unroll
  for (int mf = 0; mf < 4; ++mf) {
    const f32x4 lv = *(const f32x4*)&llds[mw*64 + mf*16 + kq*4];
    f32x4 inv;
    inv.x = __builtin_amdgcn_rcpf(lv.x); inv.y = __builtin_amdgcn_rcpf(lv.y);
    inv.z = __builtin_amdgcn_rcpf(lv.z); inv.w = __builtin_amdgcn_rcpf(lv.w);
    #pragma unroll
    for (int cf = 0; cf < 2; ++cf) {
      const int f = fh*256 + fw*32 + cf*16 + fl;
      unsigned short* cp = C1 + (size_t)(b*2048 + i0 + mw*64 + mf*16 + kq*4) * 512 + f;
      cp[0]    = f2bf(acc[mf][cf].x * inv.x);
      cp[512]  = f2bf(acc[mf][cf].y * inv.y);
      cp[1024] = f2bf(acc[mf][cf].z * inv.z);
      cp[1536] = f2bf(acc[mf][cf].w * inv.w);
    }
  }
}

// ---- Kernel D: out = elu(C1 @ W)  (B-frags from wt[f2][f1]) ------------------------------
__global__ __launch_bounds__(512, 2) void k_gemm2(const unsigned short* __restrict__ C1,
                                                  const unsigned short* __restrict__ wt,
                                                  float* __restrict__ out) {
  const int tid = threadIdx.x;
  const int w = tid >> 6, l = tid & 63;
  const int fl = l & 15, kq = l >> 4;
  const int row0 = (blockIdx.x & 7) * 2048 + (blockIdx.x >> 3) * 64;

  const unsigned short* ap[4];
  const unsigned short* bp[4];
  #pragma unroll
  for (int fr = 0; fr < 4; ++fr) ap[fr] = C1 + (size_t)(row0 + fr*16 + fl)*512 + kq*8;
  #pragma unroll
  for (int cf = 0; cf < 4; ++cf) bp[cf] = wt + (size_t)(w*64 + cf*16 + fl)*512 + kq*8;

  f32x4 acc[4][4];
  #pragma unroll
  for (int i = 0; i < 4; ++i)
    #pragma unroll
    for (int j = 0; j < 4; ++j) acc[i][j] = (f32x4){0.f,0.f,0.f,0.f};

  i32x4 ac[4], bc[4], an[4], bn[4];
  #pragma unroll
  for (int x = 0; x < 4; ++x) { ac[x] = *(const i32x4*)(ap[x]); bc[x] = *(const i32x4*)(bp[x]); }

  for (int sI = 0; sI < 16; ++sI) {
    const int sn = (sI < 15) ? sI + 1 : 15;
    #pragma unroll
    for (int x = 0; x < 4; ++x) {
      an[x] = *(const i32x4*)(ap[x] + sn*32);
      bn[x] = *(const i32x4*)(bp[x] + sn*32);
    }
    #pragma unroll
    for (int fr = 0; fr < 4; ++fr)
      #pragma unroll
      for (int cf = 0; cf < 4; ++cf)
        mfma_bf16_16x16x32(acc[fr][cf], ac[fr], bc[cf]);
    #pragma unroll
    for (int x = 0; x < 4; ++x) { ac[x] = an[x]; bc[x] = bn[x]; }
  }

  asm volatile("s_nop 7\ns_nop 7\ns_nop 7" :::);
  #pragma unroll
  for (int fr = 0; fr < 4; ++fr)
    #pragma unroll
    for (int cf = 0; cf < 4; ++cf) {
      const int f = w*64 + cf*16 + fl;
      float* op = out + (size_t)(row0 + fr*16 + kq*4) * 512 + f;
      const f32x4 v = acc[fr][cf];
      float o0 = v.x > 0.f ? v.x : __builtin_amdgcn_exp2f(v.x * LOG2E) - 1.f;
      float o1 = v.y > 0.f ? v.y : __builtin_amdgcn_exp2f(v.y * LOG2E) - 1.f;
      float o2 = v.z > 0.f ? v.z : __builtin_amdgcn_exp2f(v.z * LOG2E) - 1.f;
      float o3 = v.w > 0.f ? v.w : __builtin_amdgcn_exp2f(v.w * LOG2E) - 1.f;
      __builtin_nontemporal_store(o0, op);
      __builtin_nontemporal_store(o1, op + 512);
      __builtin_nontemporal_store(o2, op + 1024);
      __builtin_nontemporal_store(o3, op + 1536);
    }
}

extern "C" void kernel_launch(void* const* d_in, const int* in_sizes, int n_in,
                              void* d_out, int out_size, void* d_ws, size_t ws_size,
                              hipStream_t stream) {
  const float* h  = (const float*)d_in[0];
  const int*  adj = (const int*)d_in[1];
  const float* W  = (const float*)d_in[2];
  const float* a  = (const float*)d_in[3];
  float* out = (float*)d_out;
  char* ws = (char*)d_ws;
  unsigned short* wt   = (unsigned short*)(ws);                      // 512*512*2      = 524288
  unsigned short* hT   = (unsigned short*)(ws + 524288);             // 8*512*2048*2   = 16777216
  unsigned short* C1   = (unsigned short*)(ws + 17301504);           // 16384*512*2    = 16777216
  float* ei            = (float*)(ws + 34078720);                    // 16384*4
  float* ej            = (float*)(ws + 34144256);                    // 16384*4
  float* v1            = (float*)(ws + 34209792);                    // 512*4
  float* v2            = (float*)(ws + 34211840);                    // 512*4
  unsigned short* adjb = (unsigned short*)(ws + 34213888);           // 8*2048*128*2   = 4194304  (~38.4MB total)

  hipLaunchKernelGGL(k_setup, dim3(416),  dim3(256),  0, stream, W, a, wt, v1, v2, ei);
  hipLaunchKernelGGL(k_pack,  dim3(8192), dim3(256),  0, stream, adj, adjb);
  hipLaunchKernelGGL(k_prep,  dim3(8192), dim3(256),  0, stream, h, v1, v2, hT, ei, ej);
  hipLaunchKernelGGL(k_attn,  dim3(256),  dim3(1024), 0, stream, adjb, hT, ei, ej, C1);
  hipLaunchKernelGGL(k_gemm2, dim3(256),  dim3(512),  0, stream, C1, wt, out);
}